// Round 16
// baseline (392.066 us; speedup 1.0000x reference)
//
#include <hip/hip_runtime.h>

#define TT 1024
#define NB 32
#define NJ 128
#define NI 512
#define KD 16
#define LVL 1048576        // shorts per level in WF (512*2048)
#define XPROWS 1039        // 15 zero rows + 1024
#define XPF4 1063936       // XPROWS*4096/4 float4s

typedef short bf16x8 __attribute__((ext_vector_type(8)));
typedef float floatx4 __attribute__((ext_vector_type(4)));

struct S3 { short h, m, l; };

// 3-way bf16 truncation split: v = h + m + l + O(2^-24 v). Residuals exact.
__device__ __forceinline__ S3 split3(float v) {
    S3 o;
    unsigned hb = __float_as_uint(v) & 0xFFFF0000u;
    float hf = __uint_as_float(hb);
    float r1 = v - hf;
    unsigned mb = __float_as_uint(r1) & 0xFFFF0000u;
    float mf = __uint_as_float(mb);
    float r2 = r1 - mf;
    unsigned lb = __float_as_uint(r2) & 0xFFFF0000u;
    o.h = (short)(hb >> 16);
    o.m = (short)(mb >> 16);
    o.l = (short)(lb >> 16);
    return o;
}

__device__ __forceinline__ void gload16(const void* g, void* l) {
    __builtin_amdgcn_global_load_lds(
        (const __attribute__((address_space(1))) void*)g,
        (__attribute__((address_space(3))) void*)l, 16, 0, 0);
}

// ---------------- DCLS: W in 3-level bf16 MFMA B-frag layout [R10-proven] ----------------
__global__ __launch_bounds__(256) void dcls_kern(const float* __restrict__ w,
                                                 const float* __restrict__ P,
                                                 short* __restrict__ WF) {
    int idx = blockIdx.x * 256 + threadIdx.x;   // idx = i*128 + j
    int j = idx & (NJ - 1);
    int i = idx >> 7;
    float wv = w[i * NJ + j];
    float c  = P[i * NJ + j] + (float)(KD / 2);
    float g[KD];
    float s = 0.f;
#pragma unroll
    for (int k = 0; k < KD; ++k) {
        float u = (float)k - c;
        g[k] = expf(-2.0f * u * u);
        s += g[k];
    }
    float inv = wv / (s + 1e-7f);
    size_t base = (size_t)(i >> 4) * 32768 + (size_t)(j >> 3) * 128 + (i & 15) * 8 + (j & 7);
#pragma unroll
    for (int d = 0; d < KD; ++d) {
        S3 sp = split3(g[(KD - 1) - d] * inv);   // conv flip
        size_t off = base + (size_t)d * 2048;
        WF[off]           = sp.h;
        WF[off + LVL]     = sp.m;
        WF[off + 2 * LVL] = sp.l;
    }
}

// ---------------- x pad: xpad[tp][b][j] = (tp<15) ? 0 : x[tp-15][b][j] ----------------
__global__ __launch_bounds__(512) void pad_kern(const float* __restrict__ x,
                                                float* __restrict__ xp) {
    size_t i4 = (size_t)blockIdx.x * 512 + threadIdx.x;
    if (i4 >= XPF4) return;
    size_t off = i4 * 4;
    float4 v = make_float4(0.f, 0.f, 0.f, 0.f);
    if (off >= (size_t)15 * 4096) v = *(const float4*)(x + off - 61440);
    *(float4*)(xp + off) = v;
}

// ---------------- MFMA conv: y[t,b,i] = sum_{d,j} W[i][d*128+j] * x[t-d,b,j] ----
// 256t x 256i tile, 512 threads = 8 waves (2 wm x 4 wn, wave-tile 128x64).
// Grid 256 = 1 block/CU. Staging via global_load_lds (DMA, no stage VALU, no
// ds_write): raw fp32 x tile [256][32], double-buffered (2x32KB), bank-XOR via
// PRE-SWIZZLED SOURCE (LDS chunk c of row r holds global chunk c^(r&7); dest
// linear per gload_lds semantics). ONE barrier per K-step; all loads issued a
// full MFMA-cluster ahead -> barrier drains cheap. split3 moved into MFMA phase
// (VALU co-issues with matrix pipe). W reg double-buffered from frag-layout WF.
// 6 MFMA products: AhWh + AhWm + AmWh + AmWm + AhWl + AlWh.
__global__ __launch_bounds__(512, 2) void conv_mfma(const float* __restrict__ xpad,
                                                    const short* __restrict__ WF,
                                                    float* __restrict__ y) {
    __shared__ __align__(16) float XT0[256][32];   // 32 KB
    __shared__ __align__(16) float XT1[256][32];   // 32 KB

    const int t0 = blockIdx.x * 256;
    const int i0 = blockIdx.y * 256;
    const int b  = blockIdx.z;
    const int tid = threadIdx.x;

    const int l    = tid & 63;
    const int wv   = tid >> 6;           // wave 0..7
    const int lr16 = l & 15;
    const int kb   = l >> 4;             // k-octet 0..3
    const int wm   = wv >> 2;            // 0..1 -> 128 t-rows
    const int wn   = wv & 3;             // 0..3 -> 64 i-cols

    const int srow = tid >> 3;           // 0..63 (stage row within 64-row group)
    const int gch  = (tid & 7) ^ ((tid >> 3) & 7);   // pre-swizzled source chunk

    const short* pnf[4];
#pragma unroll
    for (int nf = 0; nf < 4; ++nf) {
        int ig = (i0 + wn * 64 + nf * 16) >> 4;
        pnf[nf] = WF + (size_t)ig * 32768 + l * 8;
    }

    floatx4 acc[8][4];
#pragma unroll
    for (int mf = 0; mf < 8; ++mf)
#pragma unroll
        for (int nf = 0; nf < 4; ++nf)
#pragma unroll
            for (int e = 0; e < 4; ++e) acc[mf][nf][e] = 0.f;

    bf16x8 W0h[4], W0m[4], W0l[4], W1h[4], W1m[4], W1l[4];

#define LOADW(K, H, M, L_) {                                                    \
    int koff = ((((K) >> 2) * 16 + ((K) & 3) * 4)) * 128;                       \
    _Pragma("unroll") for (int nf = 0; nf < 4; ++nf) {                          \
        const short* p = pnf[nf] + koff;                                        \
        H[nf]  = *(const bf16x8*)(p);                                           \
        M[nf]  = *(const bf16x8*)(p + LVL);                                     \
        L_[nf] = *(const bf16x8*)(p + 2 * LVL); } }

// 4 issues x 16B/thread = 32KB tile. LDS dest linear (base + lane*16); source
// address carries the swizzle. Row r = q*64+srow; tp = t0+r-d+15 (xpad space).
#define GLOAD(K, TILE) {                                                        \
    int dn = (K) >> 2, j0n = ((K) & 3) << 5;                                    \
    _Pragma("unroll") for (int q = 0; q < 4; ++q) {                             \
        int r  = q * 64 + srow;                                                 \
        int tp = t0 + r - dn + 15;                                              \
        const float* src = xpad + ((size_t)tp * NB + b) * NJ + j0n + gch * 4;   \
        gload16(src, (char*)&TILE[0][0] + q * 8192 + tid * 16); } }

#define DOMFMA(TILE, WH, WM, WL) {                                              \
    _Pragma("unroll") for (int mf = 0; mf < 8; ++mf) {                          \
        int row = wm * 128 + mf * 16 + lr16;                                    \
        int key = lr16 & 7;                                                     \
        const float* rp = &TILE[row][0];                                        \
        int c0 = (((2 * kb)     ^ key) << 2);                                   \
        int c1 = (((2 * kb + 1) ^ key) << 2);                                   \
        float4 fa = *(const float4*)(rp + c0);                                  \
        float4 fb = *(const float4*)(rp + c1);                                  \
        S3 s0 = split3(fa.x), s1 = split3(fa.y), s2 = split3(fa.z),             \
           s3 = split3(fa.w), s4 = split3(fb.x), s5 = split3(fb.y),             \
           s6 = split3(fb.z), s7 = split3(fb.w);                                \
        bf16x8 ah, am, al;                                                      \
        ah[0]=s0.h; ah[1]=s1.h; ah[2]=s2.h; ah[3]=s3.h;                         \
        ah[4]=s4.h; ah[5]=s5.h; ah[6]=s6.h; ah[7]=s7.h;                         \
        am[0]=s0.m; am[1]=s1.m; am[2]=s2.m; am[3]=s3.m;                         \
        am[4]=s4.m; am[5]=s5.m; am[6]=s6.m; am[7]=s7.m;                         \
        al[0]=s0.l; al[1]=s1.l; al[2]=s2.l; al[3]=s3.l;                         \
        al[4]=s4.l; al[5]=s5.l; al[6]=s6.l; al[7]=s7.l;                         \
        _Pragma("unroll") for (int nf = 0; nf < 4; ++nf)                        \
            acc[mf][nf] = __builtin_amdgcn_mfma_f32_16x16x32_bf16(ah, WH[nf], acc[mf][nf], 0, 0, 0); \
        _Pragma("unroll") for (int nf = 0; nf < 4; ++nf)                        \
            acc[mf][nf] = __builtin_amdgcn_mfma_f32_16x16x32_bf16(ah, WM[nf], acc[mf][nf], 0, 0, 0); \
        _Pragma("unroll") for (int nf = 0; nf < 4; ++nf)                        \
            acc[mf][nf] = __builtin_amdgcn_mfma_f32_16x16x32_bf16(am, WH[nf], acc[mf][nf], 0, 0, 0); \
        _Pragma("unroll") for (int nf = 0; nf < 4; ++nf)                        \
            acc[mf][nf] = __builtin_amdgcn_mfma_f32_16x16x32_bf16(am, WM[nf], acc[mf][nf], 0, 0, 0); \
        _Pragma("unroll") for (int nf = 0; nf < 4; ++nf)                        \
            acc[mf][nf] = __builtin_amdgcn_mfma_f32_16x16x32_bf16(ah, WL[nf], acc[mf][nf], 0, 0, 0); \
        _Pragma("unroll") for (int nf = 0; nf < 4; ++nf)                        \
            acc[mf][nf] = __builtin_amdgcn_mfma_f32_16x16x32_bf16(al, WH[nf], acc[mf][nf], 0, 0, 0); \
    } }

    // prologue: DMA tile 0, W frags 0; barrier (drains the DMA)
    GLOAD(0, XT0)
    LOADW(0, W0h, W0m, W0l)
    __syncthreads();

#pragma unroll 1
    for (int kk = 0; kk < 64; kk += 2) {
        // step kk: prefetch kk+1 into XT1/W1 (in flight across the barrier), compute XT0/W0
        if (kk + 1 < 64) { GLOAD(kk + 1, XT1) LOADW(kk + 1, W1h, W1m, W1l) }
        DOMFMA(XT0, W0h, W0m, W0l)
        __syncthreads();
        // step kk+1: prefetch kk+2 into XT0/W0, compute XT1/W1
        if (kk + 2 < 64) { GLOAD(kk + 2, XT0) LOADW(kk + 2, W0h, W0m, W0l) }
        if (kk + 1 < 64) { DOMFMA(XT1, W1h, W1m, W1l) }
        __syncthreads();
    }
#undef LOADW
#undef GLOAD
#undef DOMFMA

    // ---- epilogue: C/D layout col=lane&15, row=(lane>>4)*4+reg [m89-verified] ----
#pragma unroll
    for (int mf = 0; mf < 8; ++mf)
#pragma unroll
        for (int nf = 0; nf < 4; ++nf) {
            int ic = i0 + wn * 64 + nf * 16 + lr16;
#pragma unroll
            for (int q = 0; q < 4; ++q) {
                int t = t0 + wm * 128 + mf * 16 + kb * 4 + q;
                y[((size_t)t * NB + b) * NI + ic] = acc[mf][nf][q];
            }
        }
}

// ---------------- BN stats pass 1: per-block partial sum/sumsq over 128 rows ----
__global__ __launch_bounds__(256) void red1(const float* __restrict__ y,
                                            float* __restrict__ part) {
    int r0 = blockIdx.x * 128;
    int c  = threadIdx.x;
    float s0 = 0.f, q0 = 0.f, s1 = 0.f, q1 = 0.f;
#pragma unroll 4
    for (int r = 0; r < 128; ++r) {
        float v0 = y[(size_t)(r0 + r) * NI + c];
        float v1 = y[(size_t)(r0 + r) * NI + c + 256];
        s0 += v0; q0 = fmaf(v0, v0, q0);
        s1 += v1; q1 = fmaf(v1, v1, q1);
    }
    part[blockIdx.x * NI + c]            = s0;
    part[blockIdx.x * NI + c + 256]      = s1;
    part[256 * NI + blockIdx.x * NI + c]       = q0;
    part[256 * NI + blockIdx.x * NI + c + 256] = q1;
}

// ---------------- BN stats pass 2: combine partials (double), emit scale/bias ----
__global__ __launch_bounds__(512) void red2(const float* __restrict__ part,
                                            const float* __restrict__ gamma,
                                            const float* __restrict__ bbeta,
                                            float* __restrict__ sb) {
    int c = threadIdx.x;
    double s = 0.0, q = 0.0;
#pragma unroll 8
    for (int p = 0; p < 256; ++p) {
        s += (double)part[p * NI + c];
        q += (double)part[256 * NI + p * NI + c];
    }
    double mean = s / 32768.0;
    double var  = q / 32768.0 - mean * mean;
    double scale = (double)gamma[c] / sqrt(var + 1e-5);
    sb[c]      = (float)scale;
    sb[NI + c] = (float)((double)bbeta[c] - mean * scale);
}

// ---------------- soft-reset LIF scan, in-place over y (=d_out) ----------------
__global__ __launch_bounds__(64) void scan_kern(float* __restrict__ y,
                                                const float* __restrict__ sb,
                                                const float* __restrict__ beta,
                                                const float* __restrict__ U0) {
    int g = blockIdx.x * 64 + threadIdx.x;   // 0..16383 = b*512 + i
    int i = g & (NI - 1);
    float scale = sb[i];
    float bias  = sb[NI + i];
    float bet = beta[i];
    float omb = 1.f - bet;
    float u = U0[g];
    float s = 0.f;
    float* yp = y + g;

    float A[32], Bv[32];
#pragma unroll
    for (int r = 0; r < 32; ++r) A[r] = yp[(size_t)r * 16384];

    for (int t0 = 0; t0 < TT; t0 += 64) {
#pragma unroll
        for (int r = 0; r < 32; ++r) Bv[r] = yp[(size_t)(t0 + 32 + r) * 16384];
#pragma unroll
        for (int r = 0; r < 32; ++r) {
            float z = fmaf(A[r], scale, bias);
            u = fmaf(bet, u - s, omb * z);
            s = (u >= 1.f) ? 1.f : 0.f;
            yp[(size_t)(t0 + r) * 16384] = s;
        }
        if (t0 + 64 < TT) {
#pragma unroll
            for (int r = 0; r < 32; ++r) A[r] = yp[(size_t)(t0 + 64 + r) * 16384];
        }
#pragma unroll
        for (int r = 0; r < 32; ++r) {
            float z = fmaf(Bv[r], scale, bias);
            u = fmaf(bet, u - s, omb * z);
            s = (u >= 1.f) ? 1.f : 0.f;
            yp[(size_t)(t0 + 32 + r) * 16384] = s;
        }
    }
}

extern "C" void kernel_launch(void* const* d_in, const int* in_sizes, int n_in,
                              void* d_out, int out_size, void* d_ws, size_t ws_size,
                              hipStream_t stream) {
    const float* x       = (const float*)d_in[0];
    const float* delay_w = (const float*)d_in[1];
    const float* delay_P = (const float*)d_in[2];
    const float* beta    = (const float*)d_in[3];
    const float* bn_g    = (const float*)d_in[4];
    const float* bn_b    = (const float*)d_in[5];
    const float* U0      = (const float*)d_in[6];
    float* y = (float*)d_out;

    // ws layout (~23 MiB; ws_size >= 30 MiB confirmed by R12's XF path running):
    // WF [0, 6 MiB) ; xpad [6 MiB, ~23 MiB). part/sb ALIAS WF (stream-serialized;
    // every buffer fully rewritten before each read -> deterministic under replay).
    short* WF   = (short*)d_ws;
    float* xpad = (float*)d_ws + 3 * (size_t)LVL / 2;   // 6 MiB / 4B
    float* part = (float*)d_ws;
    float* sb   = (float*)d_ws + 2 * 256 * NI;

    dcls_kern<<<dim3(NI * NJ / 256), dim3(256), 0, stream>>>(delay_w, delay_P, WF);
    pad_kern<<<dim3((XPF4 + 511) / 512), dim3(512), 0, stream>>>(x, xpad);
    conv_mfma<<<dim3(TT / 256, NI / 256, NB), dim3(512), 0, stream>>>(xpad, WF, y);
    red1<<<dim3(TT * NB / 128), dim3(256), 0, stream>>>(y, part);
    red2<<<dim3(1), dim3(512), 0, stream>>>(part, bn_g, bn_b, sb);
    scan_kern<<<dim3(NB * NI / 64), dim3(64), 0, stream>>>(y, sb, beta, U0);
}